// Round 7
// baseline (213.401 us; speedup 1.0000x reference)
//
#include <hip/hip_runtime.h>

// ---------------------------------------------------------------------------
// Attention forward: out = softmax((X Wq^T + bq)(X Wk^T + bk)^T / 8) (X Wv^T + bv)
// B=2, S=2048, H=1024, NH=16, HD=64.  All matmuls in bf16 MFMA, fp32 accum.
// Round 7: attn DS-bandwidth fix: 2-wave blocks, 32 q-rows/wave (K/V frags are
// q-invariant -> LDS bytes per q halved).  Softmax constant folded away
// entirely (Q pre-scaled by L2E/8 in GEMM; p = exp2(sT), common factor
// cancels in the l-normalization).  P packed via v_cvt_pk_bf16_f32.
// ---------------------------------------------------------------------------

typedef __attribute__((ext_vector_type(8))) short bf16x8;
typedef __attribute__((ext_vector_type(4))) short bf16x4;
typedef __attribute__((ext_vector_type(4))) float f32x4;

#define L2E 1.44269504088896340736f

__device__ __forceinline__ f32x4 mfma16(bf16x4 a, bf16x4 b, f32x4 c) {
#if defined(__AMDGCN__)
  return __builtin_amdgcn_mfma_f32_16x16x16bf16_1k(a, b, c, 0, 0, 0);
#else
  return c;  // host pass never executes device code
#endif
}

__device__ __forceinline__ unsigned short f2bf(float x) {  // RNE
  union { float f; unsigned int u; } a; a.f = x;
  unsigned int r = (a.u + 0x7fffu + ((a.u >> 16) & 1u)) >> 16;
  return (unsigned short)r;
}
__device__ __forceinline__ unsigned int fbits(float x) {
  union { float f; unsigned int u; } a; a.f = x; return a.u;
}

// pack 4 fp32 -> 4 bf16 (A-operand order) with HW packed convert if present
__device__ __forceinline__ bf16x4 pack_bf16x4(float p0, float p1, float p2, float p3) {
#if defined(__AMDGCN__) && __has_builtin(__builtin_amdgcn_cvt_pk_bf16_f32)
  typedef __attribute__((ext_vector_type(2))) __bf16 bf16x2_t;
  union { bf16x2_t h[2]; bf16x4 v; } pk;
  pk.h[0] = __builtin_amdgcn_cvt_pk_bf16_f32(p0, p1);
  pk.h[1] = __builtin_amdgcn_cvt_pk_bf16_f32(p2, p3);
  return pk.v;
#else
  unsigned u0 = fbits(p0) + 0x8000u, u1 = fbits(p1) + 0x8000u;
  unsigned u2 = fbits(p2) + 0x8000u, u3 = fbits(p3) + 0x8000u;
  union { unsigned u[2]; bf16x4 v; } pk;
  pk.u[0] = __builtin_amdgcn_perm(u1, u0, 0x07060302u);
  pk.u[1] = __builtin_amdgcn_perm(u3, u2, 0x07060302u);
  return pk.v;
#endif
}

__device__ __forceinline__ void gl_lds16(const unsigned short* g, unsigned short* l) {
  __builtin_amdgcn_global_load_lds(
      (const __attribute__((address_space(1))) void*)g,
      (__attribute__((address_space(3))) void*)l, 16, 0, 0);
}

// ---------------------------------------------------------------------------
// Kernel 1: fp32 -> bf16 conversion of hidden + the three weight matrices.
// ---------------------------------------------------------------------------
__global__ __launch_bounds__(256) void convert_all(
    const float* __restrict__ hidden, const float* __restrict__ Wq,
    const float* __restrict__ Wk, const float* __restrict__ Wv,
    unsigned short* __restrict__ Xb, unsigned short* __restrict__ Wqb,
    unsigned short* __restrict__ Wkb, unsigned short* __restrict__ Wvb) {
  int i = blockIdx.x * 256 + threadIdx.x;
  const float* src; unsigned short* dst; int off;
  if (i < 1048576)      { src = hidden; dst = Xb;  off = i; }
  else if (i < 1310720) { src = Wq;     dst = Wqb; off = i - 1048576; }
  else if (i < 1572864) { src = Wk;     dst = Wkb; off = i - 1310720; }
  else                  { src = Wv;     dst = Wvb; off = i - 1572864; }
  float4 v = ((const float4*)src)[off];
  ushort4 o;
  o.x = f2bf(v.x); o.y = f2bf(v.y); o.z = f2bf(v.z); o.w = f2bf(v.w);
  ((ushort4*)dst)[off] = o;
}

// ---------------------------------------------------------------------------
// Kernel 2: QKV projection GEMM.  Out[m,n] = sum_k A[m,k] * B[n,k]  (+bias)
//   z==0: A=X, B=Wq -> Qh [bh][s][d], pre-scaled L2E/8 (softmax fold)
//   z==1: A=X, B=Wk -> Kh [bh][s][d]
//   z==2: A=Wv, B=X -> Vh [bh][d][s]   (V TRANSPOSED, stores stay coalesced)
// 128x128 tile, BK=64, 256 threads, 16B-block XOR swizzle in LDS.
// 1D grid of 768; id&7 ~ XCD: each XCD owns a 1 MB X token-slab in its L2.
// ---------------------------------------------------------------------------
__global__ __launch_bounds__(256) void qkv_gemm(
    const unsigned short* __restrict__ Xb,
    const unsigned short* __restrict__ Wqb, const unsigned short* __restrict__ Wkb,
    const unsigned short* __restrict__ Wvb,
    const float* __restrict__ bq, const float* __restrict__ bk,
    const float* __restrict__ bv,
    unsigned short* __restrict__ Qh, unsigned short* __restrict__ Kh,
    unsigned short* __restrict__ Vh) {
  const int id  = blockIdx.x;          // 0..767
  const int xcd = id & 7;
  const int j   = id >> 3;             // 0..95
  const int tok = xcd * 4 + (j & 3);   // token tile 0..31
  const int k2  = j >> 2;              // 0..23
  const int ft  = k2 & 7;              // feature tile 0..7
  const int z   = k2 >> 3;             // 0..2

  const unsigned short* Ap; const unsigned short* Bp;
  const float* bias; unsigned short* Out; int m0, n0;
  if (z == 2) {
    Ap = Wvb; Bp = Xb; bias = bv; Out = Vh;
    m0 = ft * 128; n0 = tok * 128;     // m: feature, n: token
  } else {
    Ap = Xb; Bp = (z == 0) ? Wqb : Wkb; bias = (z == 0) ? bq : bk;
    Out = (z == 0) ? Qh : Kh;
    m0 = tok * 128; n0 = ft * 128;     // m: token, n: feature
  }
  const float oscale = (z == 0) ? (0.125f * L2E) : 1.0f;

  __shared__ unsigned short As[128 * 64];  // 16 KB
  __shared__ unsigned short Bs[128 * 64];  // 16 KB

  const int tid  = threadIdx.x;
  const int lane = tid & 63;
  const int w    = tid >> 6;
  const int wm   = w >> 1, wn = w & 1;
  const int quad = lane >> 4;
  const int r    = lane & 15;

  f32x4 acc[4][4];
#pragma unroll
  for (int a = 0; a < 4; a++)
#pragma unroll
    for (int c = 0; c < 4; c++) acc[a][c] = (f32x4){0.f, 0.f, 0.f, 0.f};

  for (int k0 = 0; k0 < 1024; k0 += 64) {
    __syncthreads();
#pragma unroll
    for (int i = 0; i < 4; i++) {
      int t   = w * 4 + i;
      int blk = t * 64 + lane;
      int row = blk >> 3;
      int c   = (blk & 7) ^ (row & 7);
      gl_lds16(Ap + (size_t)(m0 + row) * 1024 + k0 + c * 8, &As[t * 512]);
      gl_lds16(Bp + (size_t)(n0 + row) * 1024 + k0 + c * 8, &Bs[t * 512]);
    }
    __syncthreads();

    bf16x8 af[4][2], bfv[4][2];
#pragma unroll
    for (int mi = 0; mi < 4; mi++)
#pragma unroll
      for (int ks = 0; ks < 2; ks++) {
        int row = wm * 64 + mi * 16 + r;
        int bc  = (ks * 4 + quad) ^ (row & 7);
        af[mi][ks] = *(const bf16x8*)&As[row * 64 + bc * 8];
      }
#pragma unroll
    for (int ni = 0; ni < 4; ni++)
#pragma unroll
      for (int ks = 0; ks < 2; ks++) {
        int row = wn * 64 + ni * 16 + r;
        int bc  = (ks * 4 + quad) ^ (row & 7);
        bfv[ni][ks] = *(const bf16x8*)&Bs[row * 64 + bc * 8];
      }
#pragma unroll
    for (int mi = 0; mi < 4; mi++)
#pragma unroll
      for (int ni = 0; ni < 4; ni++) {
        acc[mi][ni] = __builtin_amdgcn_mfma_f32_16x16x32_bf16(af[mi][0], bfv[ni][0], acc[mi][ni], 0, 0, 0);
        acc[mi][ni] = __builtin_amdgcn_mfma_f32_16x16x32_bf16(af[mi][1], bfv[ni][1], acc[mi][ni], 0, 0, 0);
      }
  }

  // epilogue: C/D row = quad*4+e, col = r
  if (z == 2) {
#pragma unroll
    for (int mi = 0; mi < 4; mi++)
#pragma unroll
      for (int e = 0; e < 4; e++) {
        int m = m0 + wm * 64 + mi * 16 + quad * 4 + e;  // feature
        float bm = bias[m];
#pragma unroll
        for (int ni = 0; ni < 4; ni++) {
          int n = n0 + wn * 64 + ni * 16 + r;            // token
          int bb = n >> 11, s = n & 2047;
          int hh = m >> 6,  d = m & 63;
          float v = acc[mi][ni][e] + bm;
          Out[((size_t)(bb * 16 + hh) * 64 + d) * 2048 + s] = f2bf(v);
        }
      }
  } else {
    float biasv[4];
#pragma unroll
    for (int ni = 0; ni < 4; ni++) biasv[ni] = bias[n0 + wn * 64 + ni * 16 + r];
#pragma unroll
    for (int mi = 0; mi < 4; mi++)
#pragma unroll
      for (int ni = 0; ni < 4; ni++)
#pragma unroll
        for (int e = 0; e < 4; e++) {
          int m = m0 + wm * 64 + mi * 16 + quad * 4 + e;  // token
          int n = n0 + wn * 64 + ni * 16 + r;             // feature
          int bb = m >> 11, s = m & 2047;
          int hh = n >> 6,  d = n & 63;
          float v = (acc[mi][ni][e] + biasv[ni]) * oscale;
          Out[((size_t)(bb * 16 + hh) * 2048 + s) * 64 + d] = f2bf(v);
        }
  }
}

// ---------------------------------------------------------------------------
// Kernel 3: flash attention, folded-constant softmax, register-resident P.
// One (b,h), BQ=64, BKV=128.  2 waves per block (128 thr), wave w owns q-rows
// [w*32, w*32+32) (mi in {0,1}).  K/V fragments are q-invariant -> each wave's
// 32 KB tile read now serves 32 q-rows (DS bytes per q halved vs round 6).
//   S^T = K.Q^T (A=K frag, B=Q frag): lane holds P[q=r][kv=nc*16+quad*4+e]
//   == A-operand of 16x16x16 MFMA.  p = exp2(sT) directly (L2E folded into
//   Q scale; common 2^-C factor cancels in normalization).
// ---------------------------------------------------------------------------
__global__ __launch_bounds__(128, 2) void attn(
    const unsigned short* __restrict__ Qh, const unsigned short* __restrict__ Kh,
    const unsigned short* __restrict__ Vh, float* __restrict__ Out) {
  const int h = blockIdx.y, b = blockIdx.z;
  const int bh = b * 16 + h;
  const int q0 = blockIdx.x * 64;
  const unsigned short* Qp  = Qh + (size_t)bh * 2048 * 64;
  const unsigned short* Kp  = Kh + (size_t)bh * 2048 * 64;
  const unsigned short* VTp = Vh + (size_t)bh * 64 * 2048;   // [d][s]

  __shared__ unsigned short Ks[128 * 64];   // 16 KB, XOR swizzle c^(row&7)
  __shared__ unsigned short Vts[64 * 128];  // 16 KB, slot=(src+13*row)&15

  const int tid  = threadIdx.x;
  const int lane = tid & 63;
  const int w    = tid >> 6;          // 0..1
  const int quad = lane >> 4;
  const int r    = lane & 15;
  const int rm7  = r & 7;

  // ---- Q fragments direct from global: rows q0 + w*32 + mi*16 + r ----
  bf16x8 aq[2][2];
#pragma unroll
  for (int mi = 0; mi < 2; mi++) {
    const unsigned short* qrow = Qp + (size_t)(q0 + w * 32 + mi * 16 + r) * 64 + quad * 8;
    aq[mi][0] = *(const bf16x8*)(qrow);
    aq[mi][1] = *(const bf16x8*)(qrow + 32);
  }

  float lsum[2] = {0.f, 0.f};   // per-lane partial for q-row = r (per mi)
  f32x4 acc[2][4];
#pragma unroll
  for (int mi = 0; mi < 2; mi++)
#pragma unroll
    for (int dc = 0; dc < 4; dc++) acc[mi][dc] = (f32x4){0.f, 0.f, 0.f, 0.f};
  const f32x4 zero4 = (f32x4){0.f, 0.f, 0.f, 0.f};

  const int kx0 = quad ^ rm7;         // K frag block cols (krow&7 == r&7)
  const int kx1 = (4 + quad) ^ rm7;
  const int qh2 = quad >> 1, ql4 = (quad & 1) * 4;

  for (int kv0 = 0; kv0 < 2048; kv0 += 128) {
    __syncthreads();
    // ---- stage K (128x64) and V^T (64x128): 2048 blk16 / 128 thr ----
#pragma unroll
    for (int i = 0; i < 8; i++) {
      int blk  = i * 128 + tid;         // 0..1023
      int krow = blk >> 3;              // 0..127
      int kcs  = blk & 7;
      gl_lds16(Kp + (size_t)(kv0 + krow) * 64 + ((kcs ^ (krow & 7)) * 8), &Ks[blk * 8]);
      int vrow = blk >> 4;              // 0..63
      int vcs  = blk & 15;
      gl_lds16(VTp + (size_t)vrow * 2048 + kv0 + (((vcs + 13 * vrow) & 15) * 8), &Vts[blk * 8]);
    }
    __syncthreads();

#pragma unroll
    for (int nc = 0; nc < 8; nc++) {
      // K fragments (A operand): rows nc*16 + r -- shared across both mi
      int krow = nc * 16 + r;
      bf16x8 kf0 = *(const bf16x8*)&Ks[krow * 64 + kx0 * 8];
      bf16x8 kf1 = *(const bf16x8*)&Ks[krow * 64 + kx1 * 8];

      bf16x4 ap[2];
#pragma unroll
      for (int mi = 0; mi < 2; mi++) {
        // S^T chunk: lane holds q=r, kv=quad*4+e (already in log2 domain)
        f32x4 t0 = __builtin_amdgcn_mfma_f32_16x16x32_bf16(kf1, aq[mi][1], zero4, 0, 0, 0);
        f32x4 sT = __builtin_amdgcn_mfma_f32_16x16x32_bf16(kf0, aq[mi][0], t0, 0, 0, 0);
        float p0 = __builtin_exp2f(sT[0]);
        float p1 = __builtin_exp2f(sT[1]);
        float p2 = __builtin_exp2f(sT[2]);
        float p3 = __builtin_exp2f(sT[3]);
        lsum[mi] += (p0 + p1) + (p2 + p3);
        ap[mi] = pack_bf16x4(p0, p1, p2, p3);
      }

      // ctx += P V : V frags b64, shared across both mi
#pragma unroll
      for (int dc = 0; dc < 4; dc++) {
        int vrow = dc * 16 + r;
        int slot = (2 * nc + qh2 + 3 * vrow) & 15;
        bf16x4 vf = *(const bf16x4*)&Vts[vrow * 128 + slot * 8 + ql4];
        acc[0][dc] = mfma16(ap[0], vf, acc[0][dc]);
        acc[1][dc] = mfma16(ap[1], vf, acc[1][dc]);
      }
    }
  }

  // ---- epilogue ----
#pragma unroll
  for (int mi = 0; mi < 2; mi++) {
    float l = lsum[mi];
    l += __shfl_xor(l, 16, 64);
    l += __shfl_xor(l, 32, 64);
    lsum[mi] = l;   // lane r now holds full sum for q-row (w*32+mi*16+r)
  }
  // acc C/D layout: row(q_local) = quad*4+e, col(d_local) = r
#pragma unroll
  for (int mi = 0; mi < 2; mi++)
#pragma unroll
    for (int e = 0; e < 4; e++) {
      float l   = __shfl(lsum[mi], quad * 4 + e, 64);
      float inv = 1.f / l;
      int s = q0 + w * 32 + mi * 16 + quad * 4 + e;
#pragma unroll
      for (int dc = 0; dc < 4; dc++) {
        int d = dc * 16 + r;
        Out[(size_t)(b * 2048 + s) * 1024 + h * 64 + d] = acc[mi][dc][e] * inv;
      }
    }
}

// ---------------------------------------------------------------------------
// Workspace layout (bytes):
//   Xb @0 (8 MB), Wqb @8M (2 MB), Wkb @10M, Wvb @12M,
//   Qh @14680064 [bh][s][d] (8 MB, pre-scaled L2E/8), Kh @23068672 [bh][s][d],
//   Vh @31457280 [bh][d][s] (TRANSPOSED).  Total ~38 MB.
// ---------------------------------------------------------------------------
extern "C" void kernel_launch(void* const* d_in, const int* in_sizes, int n_in,
                              void* d_out, int out_size, void* d_ws, size_t ws_size,
                              hipStream_t stream) {
  const float* hidden = (const float*)d_in[0];
  const float* Wq = (const float*)d_in[1];
  const float* bq = (const float*)d_in[2];
  const float* Wk = (const float*)d_in[3];
  const float* bk = (const float*)d_in[4];
  const float* Wv = (const float*)d_in[5];
  const float* bv = (const float*)d_in[6];
  float* out = (float*)d_out;

  char* ws = (char*)d_ws;
  unsigned short* Xb  = (unsigned short*)(ws + 0);
  unsigned short* Wqb = (unsigned short*)(ws + 8388608);
  unsigned short* Wkb = (unsigned short*)(ws + 10485760);
  unsigned short* Wvb = (unsigned short*)(ws + 12582912);
  unsigned short* Qhp = (unsigned short*)(ws + 14680064);
  unsigned short* Khp = (unsigned short*)(ws + 23068672);
  unsigned short* Vhp = (unsigned short*)(ws + 31457280);

  convert_all<<<7168, 256, 0, stream>>>(hidden, Wq, Wk, Wv, Xb, Wqb, Wkb, Wvb);
  qkv_gemm<<<768, 256, 0, stream>>>(Xb, Wqb, Wkb, Wvb, bq, bk, bv,
                                    Qhp, Khp, Vhp);
  attn<<<dim3(32, 16, 2), 128, 0, stream>>>(Qhp, Khp, Vhp, out);
}

// Round 8
// 198.547 us; speedup vs baseline: 1.0748x; 1.0748x over previous
//
#include <hip/hip_runtime.h>

// ---------------------------------------------------------------------------
// Attention forward: out = softmax((X Wq^T + bq)(X Wk^T + bk)^T / 8) (X Wv^T + bv)
// B=2, S=2048, H=1024, NH=16, HD=64.  All matmuls in bf16 MFMA, fp32 accum.
// Round 8: split-KV x2 flash attention for full occupancy (32 waves/CU) --
// static-max softmax makes partials trivially mergeable: out=(a0+a1)/(l0+l1).
// Keeps R6 block shape (4 waves x 16 q-rows, BKV=64) + R7 numeric wins
// (L2E folded into Q scale, v_cvt_pk_bf16_f32 pack).
// ---------------------------------------------------------------------------

typedef __attribute__((ext_vector_type(8))) short bf16x8;
typedef __attribute__((ext_vector_type(4))) short bf16x4;
typedef __attribute__((ext_vector_type(4))) float f32x4;

#define L2E 1.44269504088896340736f

__device__ __forceinline__ f32x4 mfma16(bf16x4 a, bf16x4 b, f32x4 c) {
#if defined(__AMDGCN__)
  return __builtin_amdgcn_mfma_f32_16x16x16bf16_1k(a, b, c, 0, 0, 0);
#else
  return c;  // host pass never executes device code
#endif
}

__device__ __forceinline__ unsigned short f2bf(float x) {  // RNE
  union { float f; unsigned int u; } a; a.f = x;
  unsigned int r = (a.u + 0x7fffu + ((a.u >> 16) & 1u)) >> 16;
  return (unsigned short)r;
}
__device__ __forceinline__ unsigned int fbits(float x) {
  union { float f; unsigned int u; } a; a.f = x; return a.u;
}

// pack 4 fp32 -> 4 bf16 (A-operand order) with HW packed convert if present
__device__ __forceinline__ bf16x4 pack_bf16x4(float p0, float p1, float p2, float p3) {
#if defined(__AMDGCN__) && __has_builtin(__builtin_amdgcn_cvt_pk_bf16_f32)
  typedef __attribute__((ext_vector_type(2))) __bf16 bf16x2_t;
  union { bf16x2_t h[2]; bf16x4 v; } pk;
  pk.h[0] = __builtin_amdgcn_cvt_pk_bf16_f32(p0, p1);
  pk.h[1] = __builtin_amdgcn_cvt_pk_bf16_f32(p2, p3);
  return pk.v;
#else
  unsigned u0 = fbits(p0) + 0x8000u, u1 = fbits(p1) + 0x8000u;
  unsigned u2 = fbits(p2) + 0x8000u, u3 = fbits(p3) + 0x8000u;
  union { unsigned u[2]; bf16x4 v; } pk;
  pk.u[0] = __builtin_amdgcn_perm(u1, u0, 0x07060302u);
  pk.u[1] = __builtin_amdgcn_perm(u3, u2, 0x07060302u);
  return pk.v;
#endif
}

__device__ __forceinline__ void gl_lds16(const unsigned short* g, unsigned short* l) {
  __builtin_amdgcn_global_load_lds(
      (const __attribute__((address_space(1))) void*)g,
      (__attribute__((address_space(3))) void*)l, 16, 0, 0);
}

// ---------------------------------------------------------------------------
// Kernel 1: fp32 -> bf16 conversion of hidden + the three weight matrices.
// ---------------------------------------------------------------------------
__global__ __launch_bounds__(256) void convert_all(
    const float* __restrict__ hidden, const float* __restrict__ Wq,
    const float* __restrict__ Wk, const float* __restrict__ Wv,
    unsigned short* __restrict__ Xb, unsigned short* __restrict__ Wqb,
    unsigned short* __restrict__ Wkb, unsigned short* __restrict__ Wvb) {
  int i = blockIdx.x * 256 + threadIdx.x;
  const float* src; unsigned short* dst; int off;
  if (i < 1048576)      { src = hidden; dst = Xb;  off = i; }
  else if (i < 1310720) { src = Wq;     dst = Wqb; off = i - 1048576; }
  else if (i < 1572864) { src = Wk;     dst = Wkb; off = i - 1310720; }
  else                  { src = Wv;     dst = Wvb; off = i - 1572864; }
  float4 v = ((const float4*)src)[off];
  ushort4 o;
  o.x = f2bf(v.x); o.y = f2bf(v.y); o.z = f2bf(v.z); o.w = f2bf(v.w);
  ((ushort4*)dst)[off] = o;
}

// ---------------------------------------------------------------------------
// Kernel 2: QKV projection GEMM.  Out[m,n] = sum_k A[m,k] * B[n,k]  (+bias)
//   z==0: A=X, B=Wq -> Qh [bh][s][d], pre-scaled L2E/8 (softmax fold)
//   z==1: A=X, B=Wk -> Kh [bh][s][d]
//   z==2: A=Wv, B=X -> Vh [bh][d][s]   (V TRANSPOSED, stores stay coalesced)
// 128x128 tile, BK=64, 256 threads, 16B-block XOR swizzle in LDS.
// 1D grid of 768; id&7 ~ XCD: each XCD owns a 1 MB X token-slab in its L2.
// ---------------------------------------------------------------------------
__global__ __launch_bounds__(256) void qkv_gemm(
    const unsigned short* __restrict__ Xb,
    const unsigned short* __restrict__ Wqb, const unsigned short* __restrict__ Wkb,
    const unsigned short* __restrict__ Wvb,
    const float* __restrict__ bq, const float* __restrict__ bk,
    const float* __restrict__ bv,
    unsigned short* __restrict__ Qh, unsigned short* __restrict__ Kh,
    unsigned short* __restrict__ Vh) {
  const int id  = blockIdx.x;          // 0..767
  const int xcd = id & 7;
  const int j   = id >> 3;             // 0..95
  const int tok = xcd * 4 + (j & 3);   // token tile 0..31
  const int k2  = j >> 2;              // 0..23
  const int ft  = k2 & 7;              // feature tile 0..7
  const int z   = k2 >> 3;             // 0..2

  const unsigned short* Ap; const unsigned short* Bp;
  const float* bias; unsigned short* Out; int m0, n0;
  if (z == 2) {
    Ap = Wvb; Bp = Xb; bias = bv; Out = Vh;
    m0 = ft * 128; n0 = tok * 128;     // m: feature, n: token
  } else {
    Ap = Xb; Bp = (z == 0) ? Wqb : Wkb; bias = (z == 0) ? bq : bk;
    Out = (z == 0) ? Qh : Kh;
    m0 = tok * 128; n0 = ft * 128;     // m: token, n: feature
  }
  const float oscale = (z == 0) ? (0.125f * L2E) : 1.0f;

  __shared__ unsigned short As[128 * 64];  // 16 KB
  __shared__ unsigned short Bs[128 * 64];  // 16 KB

  const int tid  = threadIdx.x;
  const int lane = tid & 63;
  const int w    = tid >> 6;
  const int wm   = w >> 1, wn = w & 1;
  const int quad = lane >> 4;
  const int r    = lane & 15;

  f32x4 acc[4][4];
#pragma unroll
  for (int a = 0; a < 4; a++)
#pragma unroll
    for (int c = 0; c < 4; c++) acc[a][c] = (f32x4){0.f, 0.f, 0.f, 0.f};

  for (int k0 = 0; k0 < 1024; k0 += 64) {
    __syncthreads();
#pragma unroll
    for (int i = 0; i < 4; i++) {
      int t   = w * 4 + i;
      int blk = t * 64 + lane;
      int row = blk >> 3;
      int c   = (blk & 7) ^ (row & 7);
      gl_lds16(Ap + (size_t)(m0 + row) * 1024 + k0 + c * 8, &As[t * 512]);
      gl_lds16(Bp + (size_t)(n0 + row) * 1024 + k0 + c * 8, &Bs[t * 512]);
    }
    __syncthreads();

    bf16x8 af[4][2], bfv[4][2];
#pragma unroll
    for (int mi = 0; mi < 4; mi++)
#pragma unroll
      for (int ks = 0; ks < 2; ks++) {
        int row = wm * 64 + mi * 16 + r;
        int bc  = (ks * 4 + quad) ^ (row & 7);
        af[mi][ks] = *(const bf16x8*)&As[row * 64 + bc * 8];
      }
#pragma unroll
    for (int ni = 0; ni < 4; ni++)
#pragma unroll
      for (int ks = 0; ks < 2; ks++) {
        int row = wn * 64 + ni * 16 + r;
        int bc  = (ks * 4 + quad) ^ (row & 7);
        bfv[ni][ks] = *(const bf16x8*)&Bs[row * 64 + bc * 8];
      }
#pragma unroll
    for (int mi = 0; mi < 4; mi++)
#pragma unroll
      for (int ni = 0; ni < 4; ni++) {
        acc[mi][ni] = __builtin_amdgcn_mfma_f32_16x16x32_bf16(af[mi][0], bfv[ni][0], acc[mi][ni], 0, 0, 0);
        acc[mi][ni] = __builtin_amdgcn_mfma_f32_16x16x32_bf16(af[mi][1], bfv[ni][1], acc[mi][ni], 0, 0, 0);
      }
  }

  // epilogue: C/D row = quad*4+e, col = r
  if (z == 2) {
#pragma unroll
    for (int mi = 0; mi < 4; mi++)
#pragma unroll
      for (int e = 0; e < 4; e++) {
        int m = m0 + wm * 64 + mi * 16 + quad * 4 + e;  // feature
        float bm = bias[m];
#pragma unroll
        for (int ni = 0; ni < 4; ni++) {
          int n = n0 + wn * 64 + ni * 16 + r;            // token
          int bb = n >> 11, s = n & 2047;
          int hh = m >> 6,  d = m & 63;
          float v = acc[mi][ni][e] + bm;
          Out[((size_t)(bb * 16 + hh) * 64 + d) * 2048 + s] = f2bf(v);
        }
      }
  } else {
    float biasv[4];
#pragma unroll
    for (int ni = 0; ni < 4; ni++) biasv[ni] = bias[n0 + wn * 64 + ni * 16 + r];
#pragma unroll
    for (int mi = 0; mi < 4; mi++)
#pragma unroll
      for (int ni = 0; ni < 4; ni++)
#pragma unroll
        for (int e = 0; e < 4; e++) {
          int m = m0 + wm * 64 + mi * 16 + quad * 4 + e;  // token
          int n = n0 + wn * 64 + ni * 16 + r;             // feature
          int bb = m >> 11, s = m & 2047;
          int hh = n >> 6,  d = n & 63;
          float v = (acc[mi][ni][e] + biasv[ni]) * oscale;
          Out[((size_t)(bb * 16 + hh) * 2048 + s) * 64 + d] = f2bf(v);
        }
  }
}

// ---------------------------------------------------------------------------
// Kernel 3: flash attention, split-KV x2, static-max (folded) softmax,
// register-resident P.  One (b,h,kvhalf) per block: BQ=64 (4 waves x 16
// q-rows), BKV=64, 16 KV iters over half the sequence.  Grid 2048 blocks,
// 16 KB LDS, VGPR<=64 -> 8 blocks/CU = 32 waves/CU (full occupancy).
// Writes UNNORMALIZED partial acc (fp32) + partial l; merge kernel combines.
// ---------------------------------------------------------------------------
__global__ __launch_bounds__(256, 8) void attn(
    const unsigned short* __restrict__ Qh, const unsigned short* __restrict__ Kh,
    const unsigned short* __restrict__ Vh, float* __restrict__ accP,
    float* __restrict__ lP) {
  const int h = blockIdx.y;
  const int b = blockIdx.z >> 1;
  const int half = blockIdx.z & 1;
  const int bh = b * 16 + h;
  const int q0 = blockIdx.x * 64;
  const unsigned short* Qp  = Qh + (size_t)bh * 2048 * 64;
  const unsigned short* Kp  = Kh + (size_t)bh * 2048 * 64;
  const unsigned short* VTp = Vh + (size_t)bh * 64 * 2048;   // [d][s]

  __shared__ unsigned short Ks[64 * 64];    // 8 KB, XOR swizzle c^(row&7)
  __shared__ unsigned short Vts[64 * 64];   // 8 KB, slot=(src+5*row)&7

  const int tid  = threadIdx.x;
  const int lane = tid & 63;
  const int w    = tid >> 6;
  const int quad = lane >> 4;
  const int r    = lane & 15;
  const int rm7  = r & 7;

  // ---- Q fragments direct from global: row q0 + w*16 + r ----
  const unsigned short* qrow = Qp + (size_t)(q0 + w * 16 + r) * 64 + quad * 8;
  bf16x8 aq0 = *(const bf16x8*)(qrow);
  bf16x8 aq1 = *(const bf16x8*)(qrow + 32);

  float lsum = 0.f;             // per-lane partial for q-row = r
  f32x4 acc[4];
#pragma unroll
  for (int dc = 0; dc < 4; dc++) acc[dc] = (f32x4){0.f, 0.f, 0.f, 0.f};
  const f32x4 zero4 = (f32x4){0.f, 0.f, 0.f, 0.f};

  const int kx0 = quad ^ rm7;         // K frag block cols (krow&7 == r&7)
  const int kx1 = (4 + quad) ^ rm7;
  const int qh2 = quad >> 1, ql4 = (quad & 1) * 4;

  const int kvbase = half * 1024;
  for (int kv0 = kvbase; kv0 < kvbase + 1024; kv0 += 64) {
    __syncthreads();
    // ---- stage K (c^(row&7)) and V^T ((src+5*row)&7 slots) tiles ----
#pragma unroll
    for (int i = 0; i < 2; i++) {
      int blk = i * 256 + tid;
      int row = blk >> 3;
      int cs  = blk & 7;
      gl_lds16(Kp + (size_t)(kv0 + row) * 64 + ((cs ^ (row & 7)) * 8), &Ks[blk * 8]);
      gl_lds16(VTp + (size_t)row * 2048 + kv0 + (((cs + 5 * row) & 7) * 8), &Vts[blk * 8]);
    }
    __syncthreads();

#pragma unroll
    for (int nc = 0; nc < 4; nc++) {
      // K fragments (A operand): rows nc*16 + r
      int krow = nc * 16 + r;
      bf16x8 kf0 = *(const bf16x8*)&Ks[krow * 64 + kx0 * 8];
      bf16x8 kf1 = *(const bf16x8*)&Ks[krow * 64 + kx1 * 8];

      // S^T chunk: lane holds q=r, kv=quad*4+e (already in log2 domain)
      f32x4 t0 = __builtin_amdgcn_mfma_f32_16x16x32_bf16(kf1, aq1, zero4, 0, 0, 0);
      f32x4 sT = __builtin_amdgcn_mfma_f32_16x16x32_bf16(kf0, aq0, t0, 0, 0, 0);

      float p0 = __builtin_exp2f(sT[0]);
      float p1 = __builtin_exp2f(sT[1]);
      float p2 = __builtin_exp2f(sT[2]);
      float p3 = __builtin_exp2f(sT[3]);
      lsum += (p0 + p1) + (p2 + p3);
      bf16x4 ap = pack_bf16x4(p0, p1, p2, p3);

      // ctx += P V : B frags b64; slot = (2nc + qh2 + 3*vrow) & 7
#pragma unroll
      for (int dc = 0; dc < 4; dc++) {
        int vrow = dc * 16 + r;
        int slot = (2 * nc + qh2 + 3 * vrow) & 7;
        bf16x4 vf = *(const bf16x4*)&Vts[vrow * 64 + slot * 8 + ql4];
        acc[dc] = mfma16(ap, vf, acc[dc]);
      }
    }
  }

  // ---- epilogue: write partial l and UNNORMALIZED partial acc ----
  lsum += __shfl_xor(lsum, 16, 64);
  lsum += __shfl_xor(lsum, 32, 64);
  // lane r (any quad) now holds full partial sum for q-row w*16 + r
  if (lane < 16)
    lP[(size_t)half * 65536 + ((size_t)(b * 2048 + q0 + w * 16 + lane)) * 16 + h] = lsum;

  float* accp = accP + (size_t)half * 4194304;
#pragma unroll
  for (int e = 0; e < 4; e++) {
    int s = q0 + w * 16 + quad * 4 + e;
#pragma unroll
    for (int dc = 0; dc < 4; dc++) {
      int d = dc * 16 + r;
      accp[(size_t)(b * 2048 + s) * 1024 + h * 64 + d] = acc[dc][e];
    }
  }
}

// ---------------------------------------------------------------------------
// Kernel 4: merge the two KV halves: out = (a0 + a1) / (l0 + l1).
// 1M float4 elements; l indexed per (b*2048+s, h).
// ---------------------------------------------------------------------------
__global__ __launch_bounds__(256) void merge_halves(
    const float* __restrict__ accP, const float* __restrict__ lP,
    float* __restrict__ out) {
  int i = blockIdx.x * 256 + threadIdx.x;    // float4 index, 0..1048575
  int bs = i >> 8;                           // b*2048 + s
  int h  = (i & 255) >> 4;                   // head
  float l = lP[(size_t)bs * 16 + h] + lP[65536 + (size_t)bs * 16 + h];
  float inv = 1.f / l;
  float4 a0 = ((const float4*)accP)[i];
  float4 a1 = ((const float4*)accP)[1048576 + i];
  float4 o;
  o.x = (a0.x + a1.x) * inv;
  o.y = (a0.y + a1.y) * inv;
  o.z = (a0.z + a1.z) * inv;
  o.w = (a0.w + a1.w) * inv;
  ((float4*)out)[i] = o;
}

// ---------------------------------------------------------------------------
// Workspace layout (bytes):
//   Qh  @ 0         8388608   [bh][s][d] bf16, pre-scaled L2E/8
//   Kh  @ 8388608   8388608   [bh][s][d] bf16
//   Vh  @ 16777216  8388608   [bh][d][s] bf16 (TRANSPOSED)
//   Xb  @ 25165824  8388608   bf16 (dead after qkv_gemm)
//   Wqb @ 33554432  2097152, Wkb @ 35651584, Wvb @ 37748736 (dead after qkv)
//   accP @ 25165824 33554432  fp32 partials (overlays dead Xb/W region)
//   lP   @ 58720256 524288    fp32 partial row sums
//   total 59244544 (~56.5 MB)
// ---------------------------------------------------------------------------
extern "C" void kernel_launch(void* const* d_in, const int* in_sizes, int n_in,
                              void* d_out, int out_size, void* d_ws, size_t ws_size,
                              hipStream_t stream) {
  const float* hidden = (const float*)d_in[0];
  const float* Wq = (const float*)d_in[1];
  const float* bq = (const float*)d_in[2];
  const float* Wk = (const float*)d_in[3];
  const float* bk = (const float*)d_in[4];
  const float* Wv = (const float*)d_in[5];
  const float* bv = (const float*)d_in[6];
  float* out = (float*)d_out;

  char* ws = (char*)d_ws;
  unsigned short* Qhp = (unsigned short*)(ws + 0);
  unsigned short* Khp = (unsigned short*)(ws + 8388608);
  unsigned short* Vhp = (unsigned short*)(ws + 16777216);
  unsigned short* Xb  = (unsigned short*)(ws + 25165824);
  unsigned short* Wqb = (unsigned short*)(ws + 33554432);
  unsigned short* Wkb = (unsigned short*)(ws + 35651584);
  unsigned short* Wvb = (unsigned short*)(ws + 37748736);
  float* accP = (float*)(ws + 25165824);   // overlays Xb/W after qkv_gemm
  float* lP   = (float*)(ws + 58720256);

  convert_all<<<7168, 256, 0, stream>>>(hidden, Wq, Wk, Wv, Xb, Wqb, Wkb, Wvb);
  qkv_gemm<<<768, 256, 0, stream>>>(Xb, Wqb, Wkb, Wvb, bq, bk, bv,
                                    Qhp, Khp, Vhp);
  attn<<<dim3(32, 16, 4), 256, 0, stream>>>(Qhp, Khp, Vhp, accP, lP);
  merge_halves<<<4096, 256, 0, stream>>>(accP, lP, out);
}

// Round 9
// 184.006 us; speedup vs baseline: 1.1597x; 1.0790x over previous
//
#include <hip/hip_runtime.h>

// ---------------------------------------------------------------------------
// Attention forward: out = softmax((X Wq^T + bq)(X Wk^T + bk)^T / 8) (X Wv^T + bv)
// B=2, S=2048, H=1024, NH=16, HD=64.  All matmuls in bf16 MFMA, fp32 accum.
// Round 9: in-block split-KV (8 waves: group 0 = KV half 0, group 1 = half 1,
// same q-tile), merged through LDS -> no merge kernel, no partial traffic.
// l computed by an extra ones-column MFMA (row-sum of P in C-layout,
// replicated across lanes) -> no lsum VALU adds, no epilogue shuffles.
// ---------------------------------------------------------------------------

typedef __attribute__((ext_vector_type(8))) short bf16x8;
typedef __attribute__((ext_vector_type(4))) short bf16x4;
typedef __attribute__((ext_vector_type(4))) float f32x4;

#define L2E 1.44269504088896340736f

__device__ __forceinline__ f32x4 mfma16(bf16x4 a, bf16x4 b, f32x4 c) {
#if defined(__AMDGCN__)
  return __builtin_amdgcn_mfma_f32_16x16x16bf16_1k(a, b, c, 0, 0, 0);
#else
  return c;  // host pass never executes device code
#endif
}

__device__ __forceinline__ unsigned short f2bf(float x) {  // RNE
  union { float f; unsigned int u; } a; a.f = x;
  unsigned int r = (a.u + 0x7fffu + ((a.u >> 16) & 1u)) >> 16;
  return (unsigned short)r;
}
__device__ __forceinline__ unsigned int fbits(float x) {
  union { float f; unsigned int u; } a; a.f = x; return a.u;
}

// pack 4 fp32 -> 4 bf16 (A-operand order) with HW packed convert if present
__device__ __forceinline__ bf16x4 pack_bf16x4(float p0, float p1, float p2, float p3) {
#if defined(__AMDGCN__) && __has_builtin(__builtin_amdgcn_cvt_pk_bf16_f32)
  typedef __attribute__((ext_vector_type(2))) __bf16 bf16x2_t;
  union { bf16x2_t h[2]; bf16x4 v; } pk;
  pk.h[0] = __builtin_amdgcn_cvt_pk_bf16_f32(p0, p1);
  pk.h[1] = __builtin_amdgcn_cvt_pk_bf16_f32(p2, p3);
  return pk.v;
#else
  unsigned u0 = fbits(p0) + 0x8000u, u1 = fbits(p1) + 0x8000u;
  unsigned u2 = fbits(p2) + 0x8000u, u3 = fbits(p3) + 0x8000u;
  union { unsigned u[2]; bf16x4 v; } pk;
  pk.u[0] = __builtin_amdgcn_perm(u1, u0, 0x07060302u);
  pk.u[1] = __builtin_amdgcn_perm(u3, u2, 0x07060302u);
  return pk.v;
#endif
}

__device__ __forceinline__ void gl_lds16(const unsigned short* g, unsigned short* l) {
  __builtin_amdgcn_global_load_lds(
      (const __attribute__((address_space(1))) void*)g,
      (__attribute__((address_space(3))) void*)l, 16, 0, 0);
}

// ---------------------------------------------------------------------------
// Kernel 1: fp32 -> bf16 conversion of hidden + the three weight matrices.
// ---------------------------------------------------------------------------
__global__ __launch_bounds__(256) void convert_all(
    const float* __restrict__ hidden, const float* __restrict__ Wq,
    const float* __restrict__ Wk, const float* __restrict__ Wv,
    unsigned short* __restrict__ Xb, unsigned short* __restrict__ Wqb,
    unsigned short* __restrict__ Wkb, unsigned short* __restrict__ Wvb) {
  int i = blockIdx.x * 256 + threadIdx.x;
  const float* src; unsigned short* dst; int off;
  if (i < 1048576)      { src = hidden; dst = Xb;  off = i; }
  else if (i < 1310720) { src = Wq;     dst = Wqb; off = i - 1048576; }
  else if (i < 1572864) { src = Wk;     dst = Wkb; off = i - 1310720; }
  else                  { src = Wv;     dst = Wvb; off = i - 1572864; }
  float4 v = ((const float4*)src)[off];
  ushort4 o;
  o.x = f2bf(v.x); o.y = f2bf(v.y); o.z = f2bf(v.z); o.w = f2bf(v.w);
  ((ushort4*)dst)[off] = o;
}

// ---------------------------------------------------------------------------
// Kernel 2: QKV projection GEMM.  Out[m,n] = sum_k A[m,k] * B[n,k]  (+bias)
//   z==0: A=X, B=Wq -> Qh [bh][s][d], pre-scaled L2E/8 (softmax fold)
//   z==1: A=X, B=Wk -> Kh [bh][s][d]
//   z==2: A=Wv, B=X -> Vh [bh][d][s]   (V TRANSPOSED, stores stay coalesced)
// 128x128 tile, BK=64, 256 threads, 16B-block XOR swizzle in LDS.
// 1D grid of 768; id&7 ~ XCD: each XCD owns a 1 MB X token-slab in its L2.
// ---------------------------------------------------------------------------
__global__ __launch_bounds__(256) void qkv_gemm(
    const unsigned short* __restrict__ Xb,
    const unsigned short* __restrict__ Wqb, const unsigned short* __restrict__ Wkb,
    const unsigned short* __restrict__ Wvb,
    const float* __restrict__ bq, const float* __restrict__ bk,
    const float* __restrict__ bv,
    unsigned short* __restrict__ Qh, unsigned short* __restrict__ Kh,
    unsigned short* __restrict__ Vh) {
  const int id  = blockIdx.x;          // 0..767
  const int xcd = id & 7;
  const int j   = id >> 3;             // 0..95
  const int tok = xcd * 4 + (j & 3);   // token tile 0..31
  const int k2  = j >> 2;              // 0..23
  const int ft  = k2 & 7;              // feature tile 0..7
  const int z   = k2 >> 3;             // 0..2

  const unsigned short* Ap; const unsigned short* Bp;
  const float* bias; unsigned short* Out; int m0, n0;
  if (z == 2) {
    Ap = Wvb; Bp = Xb; bias = bv; Out = Vh;
    m0 = ft * 128; n0 = tok * 128;     // m: feature, n: token
  } else {
    Ap = Xb; Bp = (z == 0) ? Wqb : Wkb; bias = (z == 0) ? bq : bk;
    Out = (z == 0) ? Qh : Kh;
    m0 = tok * 128; n0 = ft * 128;     // m: token, n: feature
  }
  const float oscale = (z == 0) ? (0.125f * L2E) : 1.0f;

  __shared__ unsigned short As[128 * 64];  // 16 KB
  __shared__ unsigned short Bs[128 * 64];  // 16 KB

  const int tid  = threadIdx.x;
  const int lane = tid & 63;
  const int w    = tid >> 6;
  const int wm   = w >> 1, wn = w & 1;
  const int quad = lane >> 4;
  const int r    = lane & 15;

  f32x4 acc[4][4];
#pragma unroll
  for (int a = 0; a < 4; a++)
#pragma unroll
    for (int c = 0; c < 4; c++) acc[a][c] = (f32x4){0.f, 0.f, 0.f, 0.f};

  for (int k0 = 0; k0 < 1024; k0 += 64) {
    __syncthreads();
#pragma unroll
    for (int i = 0; i < 4; i++) {
      int t   = w * 4 + i;
      int blk = t * 64 + lane;
      int row = blk >> 3;
      int c   = (blk & 7) ^ (row & 7);
      gl_lds16(Ap + (size_t)(m0 + row) * 1024 + k0 + c * 8, &As[t * 512]);
      gl_lds16(Bp + (size_t)(n0 + row) * 1024 + k0 + c * 8, &Bs[t * 512]);
    }
    __syncthreads();

    bf16x8 af[4][2], bfv[4][2];
#pragma unroll
    for (int mi = 0; mi < 4; mi++)
#pragma unroll
      for (int ks = 0; ks < 2; ks++) {
        int row = wm * 64 + mi * 16 + r;
        int bc  = (ks * 4 + quad) ^ (row & 7);
        af[mi][ks] = *(const bf16x8*)&As[row * 64 + bc * 8];
      }
#pragma unroll
    for (int ni = 0; ni < 4; ni++)
#pragma unroll
      for (int ks = 0; ks < 2; ks++) {
        int row = wn * 64 + ni * 16 + r;
        int bc  = (ks * 4 + quad) ^ (row & 7);
        bfv[ni][ks] = *(const bf16x8*)&Bs[row * 64 + bc * 8];
      }
#pragma unroll
    for (int mi = 0; mi < 4; mi++)
#pragma unroll
      for (int ni = 0; ni < 4; ni++) {
        acc[mi][ni] = __builtin_amdgcn_mfma_f32_16x16x32_bf16(af[mi][0], bfv[ni][0], acc[mi][ni], 0, 0, 0);
        acc[mi][ni] = __builtin_amdgcn_mfma_f32_16x16x32_bf16(af[mi][1], bfv[ni][1], acc[mi][ni], 0, 0, 0);
      }
  }

  // epilogue: C/D row = quad*4+e, col = r
  if (z == 2) {
#pragma unroll
    for (int mi = 0; mi < 4; mi++)
#pragma unroll
      for (int e = 0; e < 4; e++) {
        int m = m0 + wm * 64 + mi * 16 + quad * 4 + e;  // feature
        float bm = bias[m];
#pragma unroll
        for (int ni = 0; ni < 4; ni++) {
          int n = n0 + wn * 64 + ni * 16 + r;            // token
          int bb = n >> 11, s = n & 2047;
          int hh = m >> 6,  d = m & 63;
          float v = acc[mi][ni][e] + bm;
          Out[((size_t)(bb * 16 + hh) * 64 + d) * 2048 + s] = f2bf(v);
        }
      }
  } else {
    float biasv[4];
#pragma unroll
    for (int ni = 0; ni < 4; ni++) biasv[ni] = bias[n0 + wn * 64 + ni * 16 + r];
#pragma unroll
    for (int mi = 0; mi < 4; mi++)
#pragma unroll
      for (int ni = 0; ni < 4; ni++)
#pragma unroll
        for (int e = 0; e < 4; e++) {
          int m = m0 + wm * 64 + mi * 16 + quad * 4 + e;  // token
          int n = n0 + wn * 64 + ni * 16 + r;             // feature
          int bb = m >> 11, s = m & 2047;
          int hh = n >> 6,  d = n & 63;
          float v = (acc[mi][ni][e] + biasv[ni]) * oscale;
          Out[((size_t)(bb * 16 + hh) * 2048 + s) * 64 + d] = f2bf(v);
        }
  }
}

// ---------------------------------------------------------------------------
// Kernel 3: flash attention, in-block split-KV x2, folded static-max softmax,
// register-resident P, ones-MFMA row sums.
// 512 threads = 8 waves: group g = waves [4g,4g+4) handles KV rows
// [g*1024, g*1024+1024) of the SAME 64-row q-tile; wave w%4 owns q-subtile.
// Each group has private 16 KB K/V LDS.  After the loop, group 1 deposits
// unnormalized acc + l in LDS; group 0 merges and writes normalized output.
// Grid 1024 blocks, 32 KB LDS, ~48 VGPR -> 4 blocks/CU = 32 waves/CU.
// ---------------------------------------------------------------------------
__global__ __launch_bounds__(512, 8) void attn(
    const unsigned short* __restrict__ Qh, const unsigned short* __restrict__ Kh,
    const unsigned short* __restrict__ Vh, float* __restrict__ Out) {
  const int h = blockIdx.y, b = blockIdx.z;
  const int bh = b * 16 + h;
  const int q0 = blockIdx.x * 64;
  const unsigned short* Qp  = Qh + (size_t)bh * 2048 * 64;
  const unsigned short* Kp  = Kh + (size_t)bh * 2048 * 64;
  const unsigned short* VTp = Vh + (size_t)bh * 64 * 2048;   // [d][s]

  __shared__ unsigned short SM[2][2][64 * 64];   // [group][K,V][..]  32 KB

  const int tid  = threadIdx.x;       // 0..511
  const int lane = tid & 63;
  const int w8   = tid >> 6;          // 0..7
  const int half = w8 >> 2;           // KV half
  const int w    = w8 & 3;            // q-subtile
  const int ltid = tid & 255;         // tid within group
  const int quad = lane >> 4;
  const int r    = lane & 15;
  const int rm7  = r & 7;

  unsigned short* Ks  = &SM[half][0][0];
  unsigned short* Vts = &SM[half][1][0];

  // ---- Q fragments direct from global: row q0 + w*16 + r ----
  const unsigned short* qrow = Qp + (size_t)(q0 + w * 16 + r) * 64 + quad * 8;
  bf16x8 aq0 = *(const bf16x8*)(qrow);
  bf16x8 aq1 = *(const bf16x8*)(qrow + 32);

  f32x4 lacc = (f32x4){0.f, 0.f, 0.f, 0.f};   // row-sums of P (C-layout)
  f32x4 acc[4];
#pragma unroll
  for (int dc = 0; dc < 4; dc++) acc[dc] = (f32x4){0.f, 0.f, 0.f, 0.f};
  const f32x4 zero4 = (f32x4){0.f, 0.f, 0.f, 0.f};

  union { unsigned u[2]; bf16x4 v; } ou;
  ou.u[0] = 0x3F803F80u; ou.u[1] = 0x3F803F80u;
  const bf16x4 ones = ou.v;                     // B-frag of 1.0 bf16

  const int kx0 = quad ^ rm7;         // K frag block cols (krow&7 == r&7)
  const int kx1 = (4 + quad) ^ rm7;
  const int qh2 = quad >> 1, ql4 = (quad & 1) * 4;

  const int kvbase = half * 1024;
  for (int kv0 = kvbase; kv0 < kvbase + 1024; kv0 += 64) {
    __syncthreads();
    // ---- stage this group's K (c^(row&7)) and V^T ((src+5*row)&7) tiles ----
#pragma unroll
    for (int i = 0; i < 2; i++) {
      int blk = i * 256 + ltid;
      int row = blk >> 3;
      int cs  = blk & 7;
      gl_lds16(Kp + (size_t)(kv0 + row) * 64 + ((cs ^ (row & 7)) * 8), &Ks[blk * 8]);
      gl_lds16(VTp + (size_t)row * 2048 + kv0 + (((cs + 5 * row) & 7) * 8), &Vts[blk * 8]);
    }
    __syncthreads();

#pragma unroll
    for (int nc = 0; nc < 4; nc++) {
      // K fragments (A operand): rows nc*16 + r
      int krow = nc * 16 + r;
      bf16x8 kf0 = *(const bf16x8*)&Ks[krow * 64 + kx0 * 8];
      bf16x8 kf1 = *(const bf16x8*)&Ks[krow * 64 + kx1 * 8];

      // S^T chunk: lane holds q=r, kv=quad*4+e (already in log2 domain)
      f32x4 t0 = __builtin_amdgcn_mfma_f32_16x16x32_bf16(kf1, aq1, zero4, 0, 0, 0);
      f32x4 sT = __builtin_amdgcn_mfma_f32_16x16x32_bf16(kf0, aq0, t0, 0, 0, 0);

      float p0 = __builtin_exp2f(sT[0]);
      float p1 = __builtin_exp2f(sT[1]);
      float p2 = __builtin_exp2f(sT[2]);
      float p3 = __builtin_exp2f(sT[3]);
      bf16x4 ap = pack_bf16x4(p0, p1, p2, p3);

      // l row-sums on the MFMA pipe (B = ones): D[q][*] = sum_kv P
      lacc = mfma16(ap, ones, lacc);

      // ctx += P V : B frags b64; slot = (2nc + qh2 + 3*vrow) & 7
#pragma unroll
      for (int dc = 0; dc < 4; dc++) {
        int vrow = dc * 16 + r;
        int slot = (2 * nc + qh2 + 3 * vrow) & 7;
        bf16x4 vf = *(const bf16x4*)&Vts[vrow * 64 + slot * 8 + ql4];
        acc[dc] = mfma16(ap, vf, acc[dc]);
      }
    }
  }

  // ---- merge: group 1 -> LDS, group 0 combines and writes ----
  // acc/lacc C-layout: row(q_local) = quad*4+e, col = r.  lacc replicated
  // across r (every column of the ones product is the same row sum).
  __syncthreads();
  float* Abuf = (float*)&SM[0][0][0];           // 64 q x 65 floats (padded)
  float* Lbuf = Abuf + 64 * 65;                 // 64 floats
  if (half == 1) {
#pragma unroll
    for (int e = 0; e < 4; e++) {
      int q = w * 16 + quad * 4 + e;
#pragma unroll
      for (int dc = 0; dc < 4; dc++)
        Abuf[q * 65 + dc * 16 + r] = acc[dc][e];
      if (r == 0) Lbuf[q] = lacc[e];
    }
  }
  __syncthreads();
  if (half == 0) {
#pragma unroll
    for (int e = 0; e < 4; e++) {
      int q = w * 16 + quad * 4 + e;
      float l = lacc[e] + Lbuf[q];              // total row sum
      float inv = 1.f / l;
      int s = q0 + q;
#pragma unroll
      for (int dc = 0; dc < 4; dc++) {
        int d = dc * 16 + r;
        float v = acc[dc][e] + Abuf[q * 65 + d];
        Out[(size_t)(b * 2048 + s) * 1024 + h * 64 + d] = v * inv;
      }
    }
  }
}

// ---------------------------------------------------------------------------
// Workspace layout (bytes):
//   Qh  @ 0         8388608   [bh][s][d] bf16, pre-scaled L2E/8
//   Kh  @ 8388608   8388608   [bh][s][d] bf16
//   Vh  @ 16777216  8388608   [bh][d][s] bf16 (TRANSPOSED)
//   Xb  @ 25165824  8388608   bf16
//   Wqb @ 33554432  2097152, Wkb @ 35651584, Wvb @ 37748736
//   total 39845888 (~38 MB)
// ---------------------------------------------------------------------------
extern "C" void kernel_launch(void* const* d_in, const int* in_sizes, int n_in,
                              void* d_out, int out_size, void* d_ws, size_t ws_size,
                              hipStream_t stream) {
  const float* hidden = (const float*)d_in[0];
  const float* Wq = (const float*)d_in[1];
  const float* bq = (const float*)d_in[2];
  const float* Wk = (const float*)d_in[3];
  const float* bk = (const float*)d_in[4];
  const float* Wv = (const float*)d_in[5];
  const float* bv = (const float*)d_in[6];
  float* out = (float*)d_out;

  char* ws = (char*)d_ws;
  unsigned short* Qhp = (unsigned short*)(ws + 0);
  unsigned short* Khp = (unsigned short*)(ws + 8388608);
  unsigned short* Vhp = (unsigned short*)(ws + 16777216);
  unsigned short* Xb  = (unsigned short*)(ws + 25165824);
  unsigned short* Wqb = (unsigned short*)(ws + 33554432);
  unsigned short* Wkb = (unsigned short*)(ws + 35651584);
  unsigned short* Wvb = (unsigned short*)(ws + 37748736);

  convert_all<<<7168, 256, 0, stream>>>(hidden, Wq, Wk, Wv, Xb, Wqb, Wkb, Wvb);
  qkv_gemm<<<768, 256, 0, stream>>>(Xb, Wqb, Wkb, Wvb, bq, bk, bv,
                                    Qhp, Khp, Vhp);
  attn<<<dim3(32, 16, 2), 512, 0, stream>>>(Qhp, Khp, Vhp, out);
}